// Round 4
// baseline (1669.120 us; speedup 1.0000x reference)
//
#include <hip/hip_runtime.h>
#include <math.h>

// SLAYFeatures: x[B, H*D] fp32, omega[R,H,D,M] fp32, quad_nodes[R], quad_weights[R]
// out[B, H*R*M] fp32.  B=65536, H=16, D=64, M=32, R=2.
//
// Wave layout: lane = r*32+m (R*M == 64). Each wave owns one head h and 64
// consecutive b rows.
//   Phase A: lane l computes row l's 1/||x|| via 16x dwordx4 loads (4KB lane
//            stride; L1 absorbs) + 64 fmac. No shfl chains, no per-row vload.
//   Phase B: per row, x values come from SMEM (s_load via readfirstlane'd
//            uniform pointer); dot is 64x inline-asm v_fmac_f32 with
//            "s"(x) "v"(w) constraints -> forces omega column to STAY in
//            VGPRs (rounds 2/3 failure: allocator spilled w[], reloading
//            per use; VGPR_Count stuck at 44).
//   rnorm for row i: one uniform v_readlane from the phase-A register.

#define HH 16
#define DD 64
#define MM 32
#define RR 2
#define BPW 64   // b rows per wave
#define WPB 4    // waves per block

__global__ __launch_bounds__(256, 4)
void slay_features_kernel(const float* __restrict__ x,
                          const float* __restrict__ omega,
                          const float* __restrict__ qn,
                          const float* __restrict__ qw,
                          float* __restrict__ out)
{
    const int tid  = threadIdx.x;
    const int lane = tid & 63;
    const int wave = tid >> 6;

    const int h     = blockIdx.x & (HH - 1);
    const int chunk = blockIdx.x >> 4;

    const int r = lane >> 5;   // 0..1
    const int m = lane & 31;   // 0..31

    // per-lane quadrature constants
    const float s_node = qn[r];
    const float sqrt2s = sqrtf(2.0f * fmaxf(s_node, 0.0f));
    const float sqw    = sqrtf(fmaxf(qw[r], 0.0f));
    const float cr     = sqw * (1.0f / (float)MM);   // inv_sqrt_m^2 * sqrt(w)

    // omega column for this lane: w[d] = omega[r, h, d, m]  (64 VGPRs)
    float w[DD];
    const float* wp = omega + ((size_t)(r * HH + h) * DD) * MM + m;
    #pragma unroll
    for (int d = 0; d < DD; ++d) w[d] = wp[(size_t)d * MM];

    const int b0 = chunk * (WPB * BPW) + wave * BPW;

    // ---- Phase A: per-lane row norms (lane l <-> row b0+l) ----
    const float4* xpa = (const float4*)(x + (size_t)(b0 + lane) * (HH * DD) + h * DD);
    float s0 = 0.f, s1 = 0.f, s2 = 0.f, s3 = 0.f;
    #pragma unroll
    for (int d4 = 0; d4 < DD / 4; ++d4) {
        float4 v = xpa[d4];
        s0 = fmaf(v.x, v.x, s0);
        s1 = fmaf(v.y, v.y, s1);
        s2 = fmaf(v.z, v.z, s2);
        s3 = fmaf(v.w, v.w, s3);
    }
    const float ss = (s0 + s1) + (s2 + s3);
    const float rnorm = 1.0f / fmaxf(sqrtf(ss), 1e-6f);   // lane l: row l's 1/||x||

    // ---- Phase B: per-row SMEM dot against VGPR-pinned omega column ----
    unsigned int base_off = (unsigned int)b0 * (HH * DD * 4u)
                          + (unsigned int)h  * (DD * 4u);
    base_off = __builtin_amdgcn_readfirstlane(base_off);

    float* orow = out + (size_t)b0 * (HH * RR * MM) + (size_t)h * (RR * MM) + lane;

    for (int i = 0; i < BPW; ++i) {
        const unsigned int off =
            __builtin_amdgcn_readfirstlane(base_off + (unsigned int)i * (HH * DD * 4u));
        const float* __restrict__ xrow = (const float*)((const char*)x + off);

        // row i's rnorm, wave-uniform (SGPR)
        const float rn = __uint_as_float(
            __builtin_amdgcn_readlane(__float_as_uint(rnorm), i));

        float a0 = 0.f, a1 = 0.f, a2 = 0.f, a3 = 0.f;
        #pragma unroll
        for (int d = 0; d < DD; d += 4) {
            asm volatile("v_fmac_f32 %0, %1, %2" : "+v"(a0) : "s"(xrow[d + 0]), "v"(w[d + 0]));
            asm volatile("v_fmac_f32 %0, %1, %2" : "+v"(a1) : "s"(xrow[d + 1]), "v"(w[d + 1]));
            asm volatile("v_fmac_f32 %0, %1, %2" : "+v"(a2) : "s"(xrow[d + 2]), "v"(w[d + 2]));
            asm volatile("v_fmac_f32 %0, %1, %2" : "+v"(a3) : "s"(xrow[d + 3]), "v"(w[d + 3]));
        }
        const float acc = (a0 + a1) + (a2 + a3);

        // ---- epilogue ----
        const float proj = acc * rn;
        float ea = fmaf(proj, sqrt2s, -s_node);
        ea = fminf(fmaxf(ea, -10.0f), 10.0f);
        const float prf = __expf(ea);
        const float res = proj * proj * prf * cr;

        __builtin_nontemporal_store(res, orow);
        orow += HH * RR * MM;
    }
}

extern "C" void kernel_launch(void* const* d_in, const int* in_sizes, int n_in,
                              void* d_out, int out_size, void* d_ws, size_t ws_size,
                              hipStream_t stream) {
    const float* x     = (const float*)d_in[0];
    const float* omega = (const float*)d_in[1];
    const float* qn    = (const float*)d_in[2];
    const float* qw    = (const float*)d_in[3];
    float* out = (float*)d_out;

    const int B = in_sizes[0] / (HH * DD);          // 65536
    const int nchunks = B / (WPB * BPW);            // 256
    dim3 grid(nchunks * HH);                        // 4096 blocks, h = bid & 15
    dim3 block(WPB * 64);                           // 256 threads

    slay_features_kernel<<<grid, block, 0, stream>>>(x, omega, qn, qw, out);
}

// Round 5
// 106.244 us; speedup vs baseline: 15.7102x; 15.7102x over previous
//
#include <hip/hip_runtime.h>
#include <math.h>

// SLAYFeatures via MFMA: out[b, h*64 + (r*32+m)] = f(proj, r), proj = x_norm . omega[r,h,:,m]
// x[B,H*D] fp32, omega[R,H,D,M] fp32. B=65536,H=16,D=64,M=32,R=2. N=R*M=64.
//
// Rounds 2-4 lesson: compiler refuses to keep a 64-deep loop-invariant omega
// column in VGPRs (sinks/spills -> 64 reloads/row). So: omega lives in LDS as
// bf16 hi/lo planes [n][k] (XOR-swizzled), read per sub-tile as b128 B-frags,
// and the dot is mfma_f32_16x16x32_bf16 (3-term hi/lo split for fp32-level
// accuracy). Norm factored out (applied to acc in epilogue), computed fp32.
//
// Block = 1 head x TILE_B rows, 4 waves; wave does 16 rows/sub-tile, 8 sub-tiles.

#define HH 16
#define DD 64
#define MM 32
#define RR 2
#define NN (RR*MM)          // 64 output cols per head
#define TILE_B 512

using short8  = __attribute__((ext_vector_type(8))) short;
using floatx4 = __attribute__((ext_vector_type(4))) float;

__device__ __forceinline__ short bf16_hi(float v) {
    unsigned u = __float_as_uint(v);
    unsigned r = (u + 0x7fffu + ((u >> 16) & 1u)) >> 16;   // RNE
    return (short)r;
}
__device__ __forceinline__ float bf16_f(short s) {
    return __uint_as_float(((unsigned)(unsigned short)s) << 16);
}

__global__ __launch_bounds__(256, 4)
void slay_mfma_kernel(const float* __restrict__ x,
                      const float* __restrict__ omega,
                      const float* __restrict__ qn,
                      const float* __restrict__ qw,
                      float* __restrict__ out)
{
    __shared__ short lds_hi[NN * DD];   // [n][k] bf16 hi plane, swizzled (8KB)
    __shared__ short lds_lo[NN * DD];   // lo plane (8KB)

    const int tid  = threadIdx.x;
    const int lane = tid & 63;
    const int h    = blockIdx.x & (HH - 1);
    const int tile = blockIdx.x >> 4;

    const int mrow = lane & 15;    // A-row / B-col / store-col index
    const int g    = lane >> 4;    // k-group 0..3

    // ---- stage omega[.,h,.,.] -> LDS bf16 hi/lo planes [n=r*32+m][k=d] ----
    #pragma unroll
    for (int i = 0; i < (RR * DD * MM) / 256; ++i) {
        int e  = i * 256 + tid;
        int rr = e >> 11;
        int d  = (e >> 5) & (DD - 1);
        int m  = e & (MM - 1);
        float v = omega[((size_t)(rr * HH + h) * DD + d) * MM + m];
        short hi = bf16_hi(v);
        short lo = bf16_hi(v - bf16_f(hi));
        int n   = rr * MM + m;
        int byt = (d * 2) ^ ((n & 7) << 4);           // XOR swizzle within 128B row
        *(short*)((char*)lds_hi + n * (DD * 2) + byt) = hi;
        *(short*)((char*)lds_lo + n * (DD * 2) + byt) = lo;
    }
    __syncthreads();

    // quadrature scalars (uniform)
    const float sn[2]  = { qn[0], qn[1] };
    const float s2s[2] = { sqrtf(2.f * fmaxf(sn[0], 0.f)), sqrtf(2.f * fmaxf(sn[1], 0.f)) };
    const float cr[2]  = { sqrtf(fmaxf(qw[0], 0.f)) * (1.f / MM),
                           sqrtf(fmaxf(qw[1], 0.f)) * (1.f / MM) };

    const int sw = (mrow & 7) << 4;   // B-frag swizzle (row n = nt*16+mrow, n&7 == mrow&7)

    for (int st = 0; st < TILE_B / 64; ++st) {
        const int b_base = tile * TILE_B + st * 64 + (tid >> 6) * 16;
        const float* xr = x + (size_t)(b_base + mrow) * (HH * DD) + h * DD;

        // ---- load 16 x values: cols kc*32 + g*8 + {0..7} ----
        float xv[16];
        *(float4*)(xv + 0)  = *(const float4*)(xr + g * 8);
        *(float4*)(xv + 4)  = *(const float4*)(xr + g * 8 + 4);
        *(float4*)(xv + 8)  = *(const float4*)(xr + 32 + g * 8);
        *(float4*)(xv + 12) = *(const float4*)(xr + 32 + g * 8 + 4);

        // ---- fp32 row norm (sum split across the 4 k-groups) ----
        float ss = 0.f;
        #pragma unroll
        for (int j = 0; j < 16; ++j) ss = fmaf(xv[j], xv[j], ss);
        ss += __shfl_xor(ss, 16, 64);
        ss += __shfl_xor(ss, 32, 64);
        const float rnorm = 1.0f / fmaxf(sqrtf(ss), 1e-6f);

        // ---- bf16 hi/lo A-fragments (raw x; norm applied in epilogue) ----
        short8 a_hi[2], a_lo[2];
        #pragma unroll
        for (int kc = 0; kc < 2; ++kc)
            #pragma unroll
            for (int j = 0; j < 8; ++j) {
                float v  = xv[kc * 8 + j];
                short hi = bf16_hi(v);
                a_hi[kc][j] = hi;
                a_lo[kc][j] = bf16_hi(v - bf16_f(hi));
            }

        // rnorm for the 4 rows this lane's acc covers (row = g*4+q)
        float rn[4];
        #pragma unroll
        for (int q = 0; q < 4; ++q) rn[q] = __shfl(rnorm, g * 4 + q, 64);

        #pragma unroll
        for (int nt = 0; nt < 4; ++nt) {
            const char* rh = (const char*)lds_hi + (nt * 16 + mrow) * (DD * 2);
            const char* rl = (const char*)lds_lo + (nt * 16 + mrow) * (DD * 2);
            const int k0 = (g * 16) ^ sw;
            const int k1 = (64 + g * 16) ^ sw;
            short8 bh0 = *(const short8*)(rh + k0);
            short8 bh1 = *(const short8*)(rh + k1);
            short8 bl0 = *(const short8*)(rl + k0);
            short8 bl1 = *(const short8*)(rl + k1);

            floatx4 acc = {0.f, 0.f, 0.f, 0.f};
            acc = __builtin_amdgcn_mfma_f32_16x16x32_bf16(a_hi[0], bh0, acc, 0, 0, 0);
            acc = __builtin_amdgcn_mfma_f32_16x16x32_bf16(a_hi[1], bh1, acc, 0, 0, 0);
            acc = __builtin_amdgcn_mfma_f32_16x16x32_bf16(a_lo[0], bh0, acc, 0, 0, 0);
            acc = __builtin_amdgcn_mfma_f32_16x16x32_bf16(a_lo[1], bh1, acc, 0, 0, 0);
            acc = __builtin_amdgcn_mfma_f32_16x16x32_bf16(a_hi[0], bl0, acc, 0, 0, 0);
            acc = __builtin_amdgcn_mfma_f32_16x16x32_bf16(a_hi[1], bl1, acc, 0, 0, 0);

            const int r = nt >> 1;
            #pragma unroll
            for (int q = 0; q < 4; ++q) {
                float proj = acc[q] * rn[q];
                float ea = fmaf(proj, s2s[r], -sn[r]);
                ea = fminf(fmaxf(ea, -10.f), 10.f);
                float res = proj * proj * __expf(ea) * cr[r];
                int brow = b_base + g * 4 + q;
                __builtin_nontemporal_store(
                    res, out + (size_t)brow * (HH * NN) + h * NN + nt * 16 + mrow);
            }
        }
    }
}

extern "C" void kernel_launch(void* const* d_in, const int* in_sizes, int n_in,
                              void* d_out, int out_size, void* d_ws, size_t ws_size,
                              hipStream_t stream) {
    const float* x     = (const float*)d_in[0];
    const float* omega = (const float*)d_in[1];
    const float* qn    = (const float*)d_in[2];
    const float* qw    = (const float*)d_in[3];
    float* out = (float*)d_out;

    const int B = in_sizes[0] / (HH * DD);     // 65536
    dim3 grid((B / TILE_B) * HH);              // 2048 blocks; h = bid & 15
    dim3 block(256);

    slay_mfma_kernel<<<grid, block, 0, stream>>>(x, omega, qn, qw, out);
}